// Round 1
// baseline (2131.544 us; speedup 1.0000x reference)
//
#include <hip/hip_runtime.h>
#include <stdint.h>

#define SEQ 2048
#define HID 4096
#define KVHID 1024
#define NHEAD 32
#define DHEAD 128
#define QK_SCALE 0.08838834764831845f
#define HEAVY 204
#define SEL_N 1844
#define NEGBIG -1e30f

typedef float f32x4 __attribute__((ext_vector_type(4)));
typedef __bf16 bf16x8 __attribute__((ext_vector_type(8)));

__device__ __forceinline__ unsigned short f2bf(float x) {
    unsigned int u = __float_as_uint(x);
    u = (u + 0x7fffu + ((u >> 16) & 1u)) >> 16;
    return (unsigned short)u;
}
__device__ __forceinline__ float bf2f(unsigned short s) {
    return __uint_as_float(((unsigned int)s) << 16);
}
__device__ __forceinline__ unsigned long long pack4(unsigned short a, unsigned short b,
                                                    unsigned short c, unsigned short d) {
    return (unsigned long long)a | ((unsigned long long)b << 16) |
           ((unsigned long long)c << 32) | ((unsigned long long)d << 48);
}

// ---------------------------------------------------------------------------
// GEMM: C[M,N] = A[M,K] @ B[K,N] (+bias). A is fp32 (split to bf16 hi/lo on the
// fly) or bf16. B is fp32, split on the fly. SPLIT=true does 3-MFMA bf16x2
// compensated product. Tiles 128x128x32, 256 threads (4 waves, 2x2 of 64x64).
// LDS layout: [row][k] with row stride 40 ushorts (80B: 16B-aligned, low-conflict).
// ---------------------------------------------------------------------------
template<bool A_BF16, bool SPLIT, int OUTMODE /*0=bf16,1=f32,2=bf16 hi+lo*/, bool BIAS>
__global__ __launch_bounds__(256) void gemm_kernel(
    const void* __restrict__ Aptr, const float* __restrict__ Bmat,
    const float* __restrict__ bias,
    void* __restrict__ C0, unsigned short* __restrict__ C1,
    int M, int N, int K)
{
    constexpr int NBUF = SPLIT ? 4 : 2;
    constexpr int BHI = SPLIT ? 2 : 1;
    __shared__ unsigned short sm[NBUF][128 * 40];

    const int tid = threadIdx.x;
    const int l = tid & 63;
    const int lr = l & 15, lg = l >> 4;
    const int w = tid >> 6;
    const int wm = (w >> 1) * 64, wn = (w & 1) * 64;
    const int m0 = blockIdx.y * 128, n0 = blockIdx.x * 128;

    const f32x4 z4 = {0.f, 0.f, 0.f, 0.f};
    f32x4 acc[4][4];
    #pragma unroll
    for (int i = 0; i < 4; ++i)
        #pragma unroll
        for (int j = 0; j < 4; ++j) acc[i][j] = z4;

    const int arow = tid >> 1, akq = (tid & 1) * 16;
    const int bn = tid & 127, bkh = (tid >> 7) * 16;

    const int nk = K >> 5;
    for (int kt = 0; kt < nk; ++kt) {
        const int k0 = kt << 5;
        __syncthreads();
        // ---- stage A tile (128 x 32) ----
        if constexpr (A_BF16) {
            const unsigned short* A = (const unsigned short*)Aptr;
            const unsigned short* ap = A + (size_t)(m0 + arow) * K + k0 + akq;
            uint4 v0 = *(const uint4*)(ap);
            uint4 v1 = *(const uint4*)(ap + 8);
            *(uint4*)(&sm[0][arow * 40 + akq]) = v0;
            *(uint4*)(&sm[0][arow * 40 + akq + 8]) = v1;
        } else {
            const float* A = (const float*)Aptr;
            const float* ap = A + (size_t)(m0 + arow) * K + k0 + akq;
            #pragma unroll
            for (int nib = 0; nib < 4; ++nib) {
                float4 v = *(const float4*)(ap + nib * 4);
                unsigned short h0 = f2bf(v.x), h1 = f2bf(v.y), h2 = f2bf(v.z), h3 = f2bf(v.w);
                *(unsigned long long*)(&sm[0][arow * 40 + akq + nib * 4]) = pack4(h0, h1, h2, h3);
                if constexpr (SPLIT) {
                    unsigned short g0 = f2bf(v.x - bf2f(h0)), g1 = f2bf(v.y - bf2f(h1));
                    unsigned short g2 = f2bf(v.z - bf2f(h2)), g3 = f2bf(v.w - bf2f(h3));
                    *(unsigned long long*)(&sm[1][arow * 40 + akq + nib * 4]) = pack4(g0, g1, g2, g3);
                }
            }
        }
        // ---- stage B tile (32 x 128), transposed to [n][k] ----
        {
            const float* bp = Bmat + (size_t)(k0 + bkh) * N + n0 + bn;
            #pragma unroll
            for (int nib = 0; nib < 4; ++nib) {
                float x0 = bp[(size_t)(nib * 4 + 0) * N];
                float x1 = bp[(size_t)(nib * 4 + 1) * N];
                float x2 = bp[(size_t)(nib * 4 + 2) * N];
                float x3 = bp[(size_t)(nib * 4 + 3) * N];
                unsigned short h0 = f2bf(x0), h1 = f2bf(x1), h2 = f2bf(x2), h3 = f2bf(x3);
                *(unsigned long long*)(&sm[BHI][bn * 40 + bkh + nib * 4]) = pack4(h0, h1, h2, h3);
                if constexpr (SPLIT) {
                    unsigned short g0 = f2bf(x0 - bf2f(h0)), g1 = f2bf(x1 - bf2f(h1));
                    unsigned short g2 = f2bf(x2 - bf2f(h2)), g3 = f2bf(x3 - bf2f(h3));
                    *(unsigned long long*)(&sm[3][bn * 40 + bkh + nib * 4]) = pack4(g0, g1, g2, g3);
                }
            }
        }
        __syncthreads();
        // ---- fragments + MFMA ----
        bf16x8 ah[4], bh[4], al[4], bl[4];
        #pragma unroll
        for (int mi = 0; mi < 4; ++mi) {
            int rr = wm + mi * 16 + lr;
            ah[mi] = *(const bf16x8*)(&sm[0][rr * 40 + lg * 8]);
            if constexpr (SPLIT) al[mi] = *(const bf16x8*)(&sm[1][rr * 40 + lg * 8]);
        }
        #pragma unroll
        for (int ni = 0; ni < 4; ++ni) {
            int rr = wn + ni * 16 + lr;
            bh[ni] = *(const bf16x8*)(&sm[BHI][rr * 40 + lg * 8]);
            if constexpr (SPLIT) bl[ni] = *(const bf16x8*)(&sm[3][rr * 40 + lg * 8]);
        }
        #pragma unroll
        for (int mi = 0; mi < 4; ++mi)
            #pragma unroll
            for (int ni = 0; ni < 4; ++ni) {
                acc[mi][ni] = __builtin_amdgcn_mfma_f32_16x16x32_bf16(ah[mi], bh[ni], acc[mi][ni], 0, 0, 0);
                if constexpr (SPLIT) {
                    acc[mi][ni] = __builtin_amdgcn_mfma_f32_16x16x32_bf16(ah[mi], bl[ni], acc[mi][ni], 0, 0, 0);
                    acc[mi][ni] = __builtin_amdgcn_mfma_f32_16x16x32_bf16(al[mi], bh[ni], acc[mi][ni], 0, 0, 0);
                }
            }
    }
    // ---- epilogue ----
    #pragma unroll
    for (int ni = 0; ni < 4; ++ni) {
        const int col = n0 + wn + ni * 16 + lr;
        float bv = 0.f;
        if constexpr (BIAS) bv = bias[col];
        #pragma unroll
        for (int mi = 0; mi < 4; ++mi) {
            #pragma unroll
            for (int r = 0; r < 4; ++r) {
                const int row = m0 + wm + mi * 16 + lg * 4 + r;
                const float x = acc[mi][ni][r] + bv;
                const size_t o = (size_t)row * N + col;
                if constexpr (OUTMODE == 1) {
                    ((float*)C0)[o] = x;
                } else if constexpr (OUTMODE == 0) {
                    ((unsigned short*)C0)[o] = f2bf(x);
                } else {
                    unsigned short hi = f2bf(x);
                    ((unsigned short*)C0)[o] = hi;
                    C1[o] = f2bf(x - bf2f(hi));
                }
            }
        }
    }
}

// ---------------------------------------------------------------------------
// V transpose: v[2048][1024] -> vT[1024][2048] (bf16), so PV B-fragments are
// contiguous-in-token 16B loads.
// ---------------------------------------------------------------------------
__global__ __launch_bounds__(256) void transpose_v(const unsigned short* __restrict__ v,
                                                   unsigned short* __restrict__ vt)
{
    __shared__ unsigned short T[64][65];
    const int r0 = blockIdx.x * 64;   // token
    const int c0 = blockIdx.y * 64;   // feature
    const int tid = threadIdx.x;
    const int cc = tid & 63, rr = tid >> 6;
    #pragma unroll
    for (int i = 0; i < 16; ++i)
        T[rr + i * 4][cc] = v[(size_t)(r0 + rr + i * 4) * KVHID + c0 + cc];
    __syncthreads();
    #pragma unroll
    for (int i = 0; i < 16; ++i) {
        const int oc = rr + i * 4;
        vt[(size_t)(c0 + oc) * SEQ + r0 + cc] = T[cc][oc];
    }
}

// ---------------------------------------------------------------------------
// Attention pass 1: per-row max m and denom l with split-bf16 QK^T.
// grid: 32 heads * 32 qblocks(64 rows); wave = 16 q rows.
// ---------------------------------------------------------------------------
__global__ __launch_bounds__(256) void attn_pass1(
    const unsigned short* __restrict__ qhi, const unsigned short* __restrict__ qlo,
    const unsigned short* __restrict__ khi, const unsigned short* __restrict__ klo,
    float* __restrict__ mbuf, float* __restrict__ lbuf)
{
    const int head = blockIdx.x >> 5, qb = blockIdx.x & 31;
    const int tid = threadIdx.x, l = tid & 63, w = tid >> 6;
    const int lr = l & 15, lg = l >> 4;
    const int q0 = qb * 64 + w * 16;
    const int kv = head >> 2;

    bf16x8 qh[4], ql4[4];
    const size_t qbase = (size_t)(q0 + lr) * HID + head * DHEAD + lg * 8;
    #pragma unroll
    for (int g = 0; g < 4; ++g) {
        qh[g] = *(const bf16x8*)(qhi + qbase + g * 32);
        ql4[g] = *(const bf16x8*)(qlo + qbase + g * 32);
    }
    float m[4] = {NEGBIG, NEGBIG, NEGBIG, NEGBIG};
    float lsum[4] = {0.f, 0.f, 0.f, 0.f};
    const int nt = q0 / 16 + 1;
    for (int kt = 0; kt < nt; ++kt) {
        f32x4 acc = {0.f, 0.f, 0.f, 0.f};
        const size_t kbase = (size_t)(kt * 16 + lr) * KVHID + kv * DHEAD + lg * 8;
        #pragma unroll
        for (int g = 0; g < 4; ++g) {
            bf16x8 kh = *(const bf16x8*)(khi + kbase + g * 32);
            bf16x8 kl = *(const bf16x8*)(klo + kbase + g * 32);
            acc = __builtin_amdgcn_mfma_f32_16x16x32_bf16(qh[g], kh, acc, 0, 0, 0);
            acc = __builtin_amdgcn_mfma_f32_16x16x32_bf16(qh[g], kl, acc, 0, 0, 0);
            acc = __builtin_amdgcn_mfma_f32_16x16x32_bf16(ql4[g], kh, acc, 0, 0, 0);
        }
        const int col = kt * 16 + lr;
        #pragma unroll
        for (int r = 0; r < 4; ++r) {
            const int qrow = q0 + lg * 4 + r;
            float s = (col <= qrow) ? acc[r] * QK_SCALE : NEGBIG;
            float tm = s;
            tm = fmaxf(tm, __shfl_xor(tm, 1));
            tm = fmaxf(tm, __shfl_xor(tm, 2));
            tm = fmaxf(tm, __shfl_xor(tm, 4));
            tm = fmaxf(tm, __shfl_xor(tm, 8));
            const float mn = fmaxf(m[r], tm);
            float e = (s > -1e29f) ? expf(s - mn) : 0.f;
            e += __shfl_xor(e, 1);
            e += __shfl_xor(e, 2);
            e += __shfl_xor(e, 4);
            e += __shfl_xor(e, 8);
            lsum[r] = lsum[r] * ((m[r] > -1e29f) ? expf(m[r] - mn) : 0.f) + e;
            m[r] = mn;
        }
    }
    if (lr == 0) {
        #pragma unroll
        for (int r = 0; r < 4; ++r) {
            const int q = q0 + lg * 4 + r;
            mbuf[head * SEQ + q] = m[r];
            lbuf[head * SEQ + q] = lsum[r];
        }
    }
}

// ---------------------------------------------------------------------------
// Attention pass 2: normalized p (fp32), O = p@V (bf16 MFMA), column sums of p
// accumulated deterministically per wave in LDS, flushed with f64 atomics.
// ---------------------------------------------------------------------------
__global__ __launch_bounds__(256) void attn_pass2(
    const unsigned short* __restrict__ qhi, const unsigned short* __restrict__ qlo,
    const unsigned short* __restrict__ khi, const unsigned short* __restrict__ klo,
    const unsigned short* __restrict__ vT,
    const float* __restrict__ mbuf, const float* __restrict__ lbuf,
    unsigned short* __restrict__ obuf, double* __restrict__ colsum)
{
    __shared__ float cs[4][SEQ];
    __shared__ unsigned short pb[4][16 * 40];
    const int head = blockIdx.x >> 5, qb = blockIdx.x & 31;
    const int tid = threadIdx.x, l = tid & 63, w = tid >> 6;
    const int lr = l & 15, lg = l >> 4;
    const int q0 = qb * 64 + w * 16;
    const int kv = head >> 2;

    for (int j = tid; j < 4 * SEQ; j += 256) ((float*)cs)[j] = 0.f;
    __syncthreads();

    bf16x8 qh[4], ql4[4];
    {
        const size_t qbase = (size_t)(q0 + lr) * HID + head * DHEAD + lg * 8;
        #pragma unroll
        for (int g = 0; g < 4; ++g) {
            qh[g] = *(const bf16x8*)(qhi + qbase + g * 32);
            ql4[g] = *(const bf16x8*)(qlo + qbase + g * 32);
        }
    }
    float m_r[4], rl[4];
    #pragma unroll
    for (int r = 0; r < 4; ++r) {
        const int q = q0 + lg * 4 + r;
        m_r[r] = mbuf[head * SEQ + q];
        rl[r] = 1.0f / lbuf[head * SEQ + q];
    }
    const f32x4 z4 = {0.f, 0.f, 0.f, 0.f};
    f32x4 o[8];
    #pragma unroll
    for (int i = 0; i < 8; ++i) o[i] = z4;

    const int nc = q0 / 32 + 1;
    for (int c = 0; c < nc; ++c) {
        #pragma unroll
        for (int half = 0; half < 2; ++half) {
            const int kt = c * 2 + half, kb = kt * 16;
            float p0, p1, p2, p3;
            if (kb <= q0 + 15) {
                f32x4 acc = z4;
                const size_t kbase = (size_t)(kb + lr) * KVHID + kv * DHEAD + lg * 8;
                #pragma unroll
                for (int g = 0; g < 4; ++g) {
                    bf16x8 kh = *(const bf16x8*)(khi + kbase + g * 32);
                    bf16x8 kl = *(const bf16x8*)(klo + kbase + g * 32);
                    acc = __builtin_amdgcn_mfma_f32_16x16x32_bf16(qh[g], kh, acc, 0, 0, 0);
                    acc = __builtin_amdgcn_mfma_f32_16x16x32_bf16(qh[g], kl, acc, 0, 0, 0);
                    acc = __builtin_amdgcn_mfma_f32_16x16x32_bf16(ql4[g], kh, acc, 0, 0, 0);
                }
                const int col = kb + lr;
                float pr[4];
                float colpart = 0.f;
                #pragma unroll
                for (int r = 0; r < 4; ++r) {
                    const int qrow = q0 + lg * 4 + r;
                    const float p = (col <= qrow) ? expf(acc[r] * QK_SCALE - m_r[r]) * rl[r] : 0.f;
                    pr[r] = p;
                    colpart += p;
                }
                colpart += __shfl_xor(colpart, 16);
                colpart += __shfl_xor(colpart, 32);
                if (l < 16) cs[w][kb + l] = colpart;
                p0 = pr[0]; p1 = pr[1]; p2 = pr[2]; p3 = pr[3];
            } else {
                p0 = p1 = p2 = p3 = 0.f;
            }
            {
                unsigned short* row0 = &pb[w][0];
                const int base = (lg * 4) * 40 + half * 16 + lr;
                row0[base] = f2bf(p0);
                row0[base + 40] = f2bf(p1);
                row0[base + 80] = f2bf(p2);
                row0[base + 120] = f2bf(p3);
            }
        }
        const bf16x8 pa = *(const bf16x8*)(&pb[w][lr * 40 + lg * 8]);
        const int c0 = c * 32;
        #pragma unroll
        for (int d0 = 0; d0 < 8; ++d0) {
            const bf16x8 vf = *(const bf16x8*)(vT + (size_t)(kv * DHEAD + d0 * 16 + lr) * SEQ + c0 + lg * 8);
            o[d0] = __builtin_amdgcn_mfma_f32_16x16x32_bf16(pa, vf, o[d0], 0, 0, 0);
        }
    }
    #pragma unroll
    for (int d0 = 0; d0 < 8; ++d0)
        #pragma unroll
        for (int r = 0; r < 4; ++r)
            obuf[(size_t)(q0 + lg * 4 + r) * HID + head * DHEAD + d0 * 16 + lr] = f2bf(o[d0][r]);
    __syncthreads();
    const int cnt = qb * 64 + 64;
    for (int j = tid; j < cnt; j += 256)
        atomicAdd(&colsum[head * SEQ + j],
                  (double)(cs[0][j] + cs[1][j] + cs[2][j] + cs[3][j]));
}

// ---------------------------------------------------------------------------
// Top-k (204 of 1844) per head, exact jax.lax.top_k semantics (stable ties).
// Writes attention_masks_next and new_scores into d_out.
// ---------------------------------------------------------------------------
__global__ __launch_bounds__(256) void topk_kernel(const double* __restrict__ colsum,
                                                   float* __restrict__ outbuf)
{
    __shared__ float sc[SEL_N];
    __shared__ unsigned char fl[SEL_N];
    __shared__ int cnt;
    const int h = blockIdx.x;
    const int tid = threadIdx.x;
    for (int j = tid; j < SEL_N; j += 256) {
        sc[j] = (float)colsum[h * SEQ + j];
        fl[j] = 0;
    }
    __syncthreads();
    unsigned int cand = 0u;
    for (int b = 30; b >= 0; --b) {
        const unsigned int t = cand | (1u << b);
        const float tv = __uint_as_float(t);
        if (tid == 0) cnt = 0;
        __syncthreads();
        int local = 0;
        for (int j = tid; j < SEL_N; j += 256) local += (sc[j] >= tv) ? 1 : 0;
        atomicAdd(&cnt, local);
        __syncthreads();
        if (cnt >= HEAVY) cand = t;
        __syncthreads();
    }
    const float v204 = __uint_as_float(cand);
    if (tid == 0) cnt = 0;
    __syncthreads();
    int local = 0;
    for (int j = tid; j < SEL_N; j += 256) {
        if (sc[j] > v204) { fl[j] = 1; local++; }
    }
    atomicAdd(&cnt, local);
    __syncthreads();
    if (tid == 0) {
        int need = HEAVY - cnt;
        for (int j = 0; j < SEL_N && need > 0; ++j) {
            if (sc[j] == v204) { fl[j] = 1; --need; }
        }
    }
    __syncthreads();
    float* mask_out = outbuf + 8388608 + h * 2049;
    float* score_out = outbuf + 8388608 + NHEAD * 2049 + h * SEQ;
    for (int j = tid; j < 2049; j += 256) {
        float mv;
        if (j >= 1845) mv = 1.f;
        else if (j < SEL_N) mv = fl[j] ? 1.f : 0.f;
        else mv = 0.f;  // j == 1844
        mask_out[j] = mv;
    }
    for (int j = tid; j < SEQ; j += 256) {
        const float cur = (float)colsum[h * SEQ + j];
        const float smv = (j >= SEL_N) ? 1.f : (fl[j] ? 1.f : 0.f);
        score_out[j] = cur * smv;
    }
}

// ---------------------------------------------------------------------------
extern "C" void kernel_launch(void* const* d_in, const int* in_sizes, int n_in,
                              void* d_out, int out_size, void* d_ws, size_t ws_size,
                              hipStream_t stream)
{
    const float* hidden = (const float*)d_in[0];
    // d_in[1] = attention_mask (causal; implemented analytically)
    const float* Wq = (const float*)d_in[2];
    const float* bq = (const float*)d_in[3];
    const float* Wk = (const float*)d_in[4];
    const float* bk = (const float*)d_in[5];
    const float* Wv = (const float*)d_in[6];
    const float* bv = (const float*)d_in[7];
    const float* Wo = (const float*)d_in[8];
    float* out = (float*)d_out;

    char* ws = (char*)d_ws;
    unsigned short* q_hi = (unsigned short*)(ws);
    unsigned short* q_lo = (unsigned short*)(ws + 16777216);
    unsigned short* k_hi = (unsigned short*)(ws + 33554432);
    unsigned short* k_lo = (unsigned short*)(ws + 37748736);
    unsigned short* v_bf = (unsigned short*)(ws + 41943040);
    unsigned short* vT   = (unsigned short*)(ws + 46137344);
    unsigned short* o_bf = (unsigned short*)(ws + 50331648);
    float* mbuf = (float*)(ws + 67108864);
    float* lbuf = (float*)(ws + 67371008);
    double* colsum = (double*)(ws + 67633152);

    dim3 blk(256);
    // Q = hs@Wq + bq  (split precision, hi/lo output)
    gemm_kernel<false, true, 2, true><<<dim3(32, 16), blk, 0, stream>>>(
        hidden, Wq, bq, q_hi, q_lo, SEQ, HID, HID);
    // K = hs@Wk + bk  (split precision)
    gemm_kernel<false, true, 2, true><<<dim3(8, 16), blk, 0, stream>>>(
        hidden, Wk, bk, k_hi, k_lo, SEQ, KVHID, HID);
    // V = hs@Wv + bv  (plain bf16)
    gemm_kernel<false, false, 0, true><<<dim3(8, 16), blk, 0, stream>>>(
        hidden, Wv, bv, v_bf, nullptr, SEQ, KVHID, HID);
    transpose_v<<<dim3(32, 16), blk, 0, stream>>>(v_bf, vT);
    attn_pass1<<<dim3(1024), blk, 0, stream>>>(q_hi, q_lo, k_hi, k_lo, mbuf, lbuf);
    hipMemsetAsync((void*)colsum, 0, (size_t)NHEAD * SEQ * sizeof(double), stream);
    attn_pass2<<<dim3(1024), blk, 0, stream>>>(q_hi, q_lo, k_hi, k_lo, vT, mbuf, lbuf, o_bf, colsum);
    topk_kernel<<<dim3(32), blk, 0, stream>>>(colsum, out);
    // out = O @ Wo  (plain bf16, fp32 output)
    gemm_kernel<true, false, 1, false><<<dim3(32, 16), blk, 0, stream>>>(
        o_bf, Wo, nullptr, out, nullptr, SEQ, HID, HID);
}

// Round 2
// 1319.320 us; speedup vs baseline: 1.6156x; 1.6156x over previous
//
#include <hip/hip_runtime.h>
#include <stdint.h>

#define SEQ 2048
#define HID 4096
#define KVHID 1024
#define NHEAD 32
#define DHEAD 128
#define QK_SCALE 0.08838834764831845f
#define HEAVY 204
#define SEL_N 1844

typedef float f32x4 __attribute__((ext_vector_type(4)));
typedef float f32x16 __attribute__((ext_vector_type(16)));
typedef __bf16 bf16x8 __attribute__((ext_vector_type(8)));

__device__ __forceinline__ unsigned short f2bf(float x) {
    unsigned int u = __float_as_uint(x);
    u = (u + 0x7fffu + ((u >> 16) & 1u)) >> 16;
    return (unsigned short)u;
}
__device__ __forceinline__ float bf2f(unsigned short s) {
    return __uint_as_float(((unsigned int)s) << 16);
}
__device__ __forceinline__ unsigned long long pack4(unsigned short a, unsigned short b,
                                                    unsigned short c, unsigned short d) {
    return (unsigned long long)a | ((unsigned long long)b << 16) |
           ((unsigned long long)c << 32) | ((unsigned long long)d << 48);
}

// ---------------------------------------------------------------------------
// GEMM: C[M,N] = A[M,K] @ B[K,N] (+bias). A is fp32 (split to bf16 hi/lo on the
// fly) or bf16. B is fp32, split on the fly. SPLIT=true does 3-MFMA bf16x2
// compensated product. Tiles 128x128x32, 256 threads (4 waves, 2x2 of 64x64).
// ---------------------------------------------------------------------------
template<bool A_BF16, bool SPLIT, int OUTMODE /*0=bf16,1=f32,2=bf16 hi+lo*/, bool BIAS>
__global__ __launch_bounds__(256) void gemm_kernel(
    const void* __restrict__ Aptr, const float* __restrict__ Bmat,
    const float* __restrict__ bias,
    void* __restrict__ C0, unsigned short* __restrict__ C1,
    int M, int N, int K)
{
    constexpr int NBUF = SPLIT ? 4 : 2;
    constexpr int BHI = SPLIT ? 2 : 1;
    __shared__ unsigned short sm[NBUF][128 * 40];

    const int tid = threadIdx.x;
    const int l = tid & 63;
    const int lr = l & 15, lg = l >> 4;
    const int w = tid >> 6;
    const int wm = (w >> 1) * 64, wn = (w & 1) * 64;
    const int m0 = blockIdx.y * 128, n0 = blockIdx.x * 128;

    const f32x4 z4 = {0.f, 0.f, 0.f, 0.f};
    f32x4 acc[4][4];
    #pragma unroll
    for (int i = 0; i < 4; ++i)
        #pragma unroll
        for (int j = 0; j < 4; ++j) acc[i][j] = z4;

    const int arow = tid >> 1, akq = (tid & 1) * 16;
    const int bn = tid & 127, bkh = (tid >> 7) * 16;

    const int nk = K >> 5;
    for (int kt = 0; kt < nk; ++kt) {
        const int k0 = kt << 5;
        __syncthreads();
        if constexpr (A_BF16) {
            const unsigned short* A = (const unsigned short*)Aptr;
            const unsigned short* ap = A + (size_t)(m0 + arow) * K + k0 + akq;
            uint4 v0 = *(const uint4*)(ap);
            uint4 v1 = *(const uint4*)(ap + 8);
            *(uint4*)(&sm[0][arow * 40 + akq]) = v0;
            *(uint4*)(&sm[0][arow * 40 + akq + 8]) = v1;
        } else {
            const float* A = (const float*)Aptr;
            const float* ap = A + (size_t)(m0 + arow) * K + k0 + akq;
            #pragma unroll
            for (int nib = 0; nib < 4; ++nib) {
                float4 v = *(const float4*)(ap + nib * 4);
                unsigned short h0 = f2bf(v.x), h1 = f2bf(v.y), h2 = f2bf(v.z), h3 = f2bf(v.w);
                *(unsigned long long*)(&sm[0][arow * 40 + akq + nib * 4]) = pack4(h0, h1, h2, h3);
                if constexpr (SPLIT) {
                    unsigned short g0 = f2bf(v.x - bf2f(h0)), g1 = f2bf(v.y - bf2f(h1));
                    unsigned short g2 = f2bf(v.z - bf2f(h2)), g3 = f2bf(v.w - bf2f(h3));
                    *(unsigned long long*)(&sm[1][arow * 40 + akq + nib * 4]) = pack4(g0, g1, g2, g3);
                }
            }
        }
        {
            const float* bp = Bmat + (size_t)(k0 + bkh) * N + n0 + bn;
            #pragma unroll
            for (int nib = 0; nib < 4; ++nib) {
                float x0 = bp[(size_t)(nib * 4 + 0) * N];
                float x1 = bp[(size_t)(nib * 4 + 1) * N];
                float x2 = bp[(size_t)(nib * 4 + 2) * N];
                float x3 = bp[(size_t)(nib * 4 + 3) * N];
                unsigned short h0 = f2bf(x0), h1 = f2bf(x1), h2 = f2bf(x2), h3 = f2bf(x3);
                *(unsigned long long*)(&sm[BHI][bn * 40 + bkh + nib * 4]) = pack4(h0, h1, h2, h3);
                if constexpr (SPLIT) {
                    unsigned short g0 = f2bf(x0 - bf2f(h0)), g1 = f2bf(x1 - bf2f(h1));
                    unsigned short g2 = f2bf(x2 - bf2f(h2)), g3 = f2bf(x3 - bf2f(h3));
                    *(unsigned long long*)(&sm[3][bn * 40 + bkh + nib * 4]) = pack4(g0, g1, g2, g3);
                }
            }
        }
        __syncthreads();
        bf16x8 ah[4], bh[4], al[4], bl[4];
        #pragma unroll
        for (int mi = 0; mi < 4; ++mi) {
            int rr = wm + mi * 16 + lr;
            ah[mi] = *(const bf16x8*)(&sm[0][rr * 40 + lg * 8]);
            if constexpr (SPLIT) al[mi] = *(const bf16x8*)(&sm[1][rr * 40 + lg * 8]);
        }
        #pragma unroll
        for (int ni = 0; ni < 4; ++ni) {
            int rr = wn + ni * 16 + lr;
            bh[ni] = *(const bf16x8*)(&sm[BHI][rr * 40 + lg * 8]);
            if constexpr (SPLIT) bl[ni] = *(const bf16x8*)(&sm[3][rr * 40 + lg * 8]);
        }
        #pragma unroll
        for (int mi = 0; mi < 4; ++mi)
            #pragma unroll
            for (int ni = 0; ni < 4; ++ni) {
                acc[mi][ni] = __builtin_amdgcn_mfma_f32_16x16x32_bf16(ah[mi], bh[ni], acc[mi][ni], 0, 0, 0);
                if constexpr (SPLIT) {
                    acc[mi][ni] = __builtin_amdgcn_mfma_f32_16x16x32_bf16(ah[mi], bl[ni], acc[mi][ni], 0, 0, 0);
                    acc[mi][ni] = __builtin_amdgcn_mfma_f32_16x16x32_bf16(al[mi], bh[ni], acc[mi][ni], 0, 0, 0);
                }
            }
    }
    #pragma unroll
    for (int ni = 0; ni < 4; ++ni) {
        const int col = n0 + wn + ni * 16 + lr;
        float bv = 0.f;
        if constexpr (BIAS) bv = bias[col];
        #pragma unroll
        for (int mi = 0; mi < 4; ++mi) {
            #pragma unroll
            for (int r = 0; r < 4; ++r) {
                const int row = m0 + wm + mi * 16 + lg * 4 + r;
                const float x = acc[mi][ni][r] + bv;
                const size_t o = (size_t)row * N + col;
                if constexpr (OUTMODE == 1) {
                    ((float*)C0)[o] = x;
                } else if constexpr (OUTMODE == 0) {
                    ((unsigned short*)C0)[o] = f2bf(x);
                } else {
                    unsigned short hi = f2bf(x);
                    ((unsigned short*)C0)[o] = hi;
                    C1[o] = f2bf(x - bf2f(hi));
                }
            }
        }
    }
}

// ---------------------------------------------------------------------------
// V transpose: v[2048][1024] -> vT[1024][2048] (bf16).
// ---------------------------------------------------------------------------
__global__ __launch_bounds__(256) void transpose_v(const unsigned short* __restrict__ v,
                                                   unsigned short* __restrict__ vt)
{
    __shared__ unsigned short T[64][65];
    const int r0 = blockIdx.x * 64;
    const int c0 = blockIdx.y * 64;
    const int tid = threadIdx.x;
    const int cc = tid & 63, rr = tid >> 6;
    #pragma unroll
    for (int i = 0; i < 16; ++i)
        T[rr + i * 4][cc] = v[(size_t)(r0 + rr + i * 4) * KVHID + c0 + cc];
    __syncthreads();
    #pragma unroll
    for (int i = 0; i < 16; ++i) {
        const int oc = rr + i * 4;
        vt[(size_t)(c0 + oc) * SEQ + r0 + cc] = T[cc][oc];
    }
}

// ---------------------------------------------------------------------------
// Fused attention: one wave per (head, 32-row q-tile). Two phases over K:
//   A: l[q] = sum_k exp(s)   (no max shift needed; |s| <= ~21)
//   B: p = exp(s)/l -> colsum (exact f32 + f64 atomics), P@V via LDS-transposed
//      bf16 P fragments and V^T B-fragments.
// 32x32x16 MFMAs, S-layout (lane&31 = k column). 3 independent split chains.
// ---------------------------------------------------------------------------
__global__ __launch_bounds__(64, 2) void attn_fused(
    const unsigned short* __restrict__ qhi, const unsigned short* __restrict__ qlo,
    const unsigned short* __restrict__ khi, const unsigned short* __restrict__ klo,
    const unsigned short* __restrict__ vT,
    unsigned short* __restrict__ obuf, double* __restrict__ colsum)
{
    __shared__ unsigned short plds[32 * 32];
    const int id = blockIdx.x;
    const int head = id >> 6;
    const int qt = 63 - ((id + head * 13) & 63);   // scrambled for CU load balance
    const int q0 = qt << 5;
    const int kv = head >> 2;
    const int lane = threadIdx.x;
    const int c = lane & 31, hi = lane >> 5;

    // Q A-fragments: row = q0+c, d = s*16 + hi*8 + j
    bf16x8 qh[8], ql[8];
    const size_t qb = (size_t)(q0 + c) * HID + head * DHEAD + hi * 8;
    #pragma unroll
    for (int s = 0; s < 8; ++s) {
        qh[s] = *(const bf16x8*)(qhi + qb + s * 16);
        ql[s] = *(const bf16x8*)(qlo + qb + s * 16);
    }
    const size_t koff = (size_t)kv * DHEAD + hi * 8;

    // ---- phase A: row sums ----
    float lp[16];
    #pragma unroll
    for (int r = 0; r < 16; ++r) lp[r] = 0.f;
    for (int kt = 0; kt <= qt; ++kt) {
        const int k0 = kt << 5;
        f32x16 s0 = {}, s1 = {}, s2 = {};
        const size_t kb = (size_t)(k0 + c) * KVHID + koff;
        #pragma unroll
        for (int s = 0; s < 8; ++s) {
            bf16x8 bh = *(const bf16x8*)(khi + kb + s * 16);
            bf16x8 bl = *(const bf16x8*)(klo + kb + s * 16);
            s0 = __builtin_amdgcn_mfma_f32_32x32x16_bf16(qh[s], bh, s0, 0, 0, 0);
            s1 = __builtin_amdgcn_mfma_f32_32x32x16_bf16(ql[s], bh, s1, 0, 0, 0);
            s2 = __builtin_amdgcn_mfma_f32_32x32x16_bf16(qh[s], bl, s2, 0, 0, 0);
        }
        if (kt < qt) {
            #pragma unroll
            for (int r = 0; r < 16; ++r)
                lp[r] += expf((s0[r] + s1[r] + s2[r]) * QK_SCALE);
        } else {
            #pragma unroll
            for (int r = 0; r < 16; ++r) {
                const int qrow = q0 + (r & 3) + 8 * (r >> 2) + 4 * hi;
                const float e = (k0 + c <= qrow)
                                    ? expf((s0[r] + s1[r] + s2[r]) * QK_SCALE) : 0.f;
                lp[r] += e;
            }
        }
    }
    float rl[16];
    #pragma unroll
    for (int r = 0; r < 16; ++r) {
        float v = lp[r];
        v += __shfl_xor(v, 1);
        v += __shfl_xor(v, 2);
        v += __shfl_xor(v, 4);
        v += __shfl_xor(v, 8);
        v += __shfl_xor(v, 16);
        rl[r] = 1.0f / v;
    }

    // ---- phase B: p, colsum, PV ----
    f32x16 oacc[4];
    #pragma unroll
    for (int f = 0; f < 4; ++f) oacc[f] = (f32x16){};
    for (int kt = 0; kt <= qt; ++kt) {
        const int k0 = kt << 5;
        f32x16 s0 = {}, s1 = {}, s2 = {};
        const size_t kb = (size_t)(k0 + c) * KVHID + koff;
        #pragma unroll
        for (int s = 0; s < 8; ++s) {
            bf16x8 bh = *(const bf16x8*)(khi + kb + s * 16);
            bf16x8 bl = *(const bf16x8*)(klo + kb + s * 16);
            s0 = __builtin_amdgcn_mfma_f32_32x32x16_bf16(qh[s], bh, s0, 0, 0, 0);
            s1 = __builtin_amdgcn_mfma_f32_32x32x16_bf16(ql[s], bh, s1, 0, 0, 0);
            s2 = __builtin_amdgcn_mfma_f32_32x32x16_bf16(qh[s], bl, s2, 0, 0, 0);
        }
        float p[16];
        float csum = 0.f;
        if (kt < qt) {
            #pragma unroll
            for (int r = 0; r < 16; ++r) {
                p[r] = expf((s0[r] + s1[r] + s2[r]) * QK_SCALE) * rl[r];
                csum += p[r];
            }
        } else {
            #pragma unroll
            for (int r = 0; r < 16; ++r) {
                const int qrow = q0 + (r & 3) + 8 * (r >> 2) + 4 * hi;
                const float e = (k0 + c <= qrow)
                                    ? expf((s0[r] + s1[r] + s2[r]) * QK_SCALE) : 0.f;
                p[r] = e * rl[r];
                csum += p[r];
            }
        }
        csum += __shfl_xor(csum, 32);
        if (hi == 0) atomicAdd(&colsum[head * SEQ + k0 + c], (double)csum);
        // P -> LDS (bf16), XOR-swizzled by (row&3) on 8-element groups
        #pragma unroll
        for (int r = 0; r < 16; ++r) {
            const int row = (r & 3) + 8 * (r >> 2) + 4 * hi;
            plds[row * 32 + (((c >> 3) ^ (r & 3)) << 3) + (c & 7)] = f2bf(p[r]);
        }
        // PV: A = P[q=c][k-sub], B = V^T fragments
        #pragma unroll
        for (int t = 0; t < 2; ++t) {
            const bf16x8 pa = *(const bf16x8*)(&plds[c * 32 + ((((t << 1) + hi) ^ (c & 3)) << 3)]);
            #pragma unroll
            for (int f = 0; f < 4; ++f) {
                const bf16x8 vf = *(const bf16x8*)(vT + (size_t)(kv * DHEAD + f * 32 + c) * SEQ
                                                   + k0 + t * 16 + hi * 8);
                oacc[f] = __builtin_amdgcn_mfma_f32_32x32x16_bf16(pa, vf, oacc[f], 0, 0, 0);
            }
        }
    }
    #pragma unroll
    for (int f = 0; f < 4; ++f)
        #pragma unroll
        for (int r = 0; r < 16; ++r) {
            const int row = q0 + (r & 3) + 8 * (r >> 2) + 4 * hi;
            obuf[(size_t)row * HID + head * DHEAD + f * 32 + c] = f2bf(oacc[f][r]);
        }
}

// ---------------------------------------------------------------------------
// Top-k (204 of 1844) per head, exact jax.lax.top_k semantics (stable ties).
// ---------------------------------------------------------------------------
__global__ __launch_bounds__(256) void topk_kernel(const double* __restrict__ colsum,
                                                   float* __restrict__ outbuf)
{
    __shared__ float sc[SEL_N];
    __shared__ unsigned char fl[SEL_N];
    __shared__ int cnt;
    const int h = blockIdx.x;
    const int tid = threadIdx.x;
    for (int j = tid; j < SEL_N; j += 256) {
        sc[j] = (float)colsum[h * SEQ + j];
        fl[j] = 0;
    }
    __syncthreads();
    unsigned int cand = 0u;
    for (int b = 30; b >= 0; --b) {
        const unsigned int t = cand | (1u << b);
        const float tv = __uint_as_float(t);
        if (tid == 0) cnt = 0;
        __syncthreads();
        int local = 0;
        for (int j = tid; j < SEL_N; j += 256) local += (sc[j] >= tv) ? 1 : 0;
        atomicAdd(&cnt, local);
        __syncthreads();
        if (cnt >= HEAVY) cand = t;
        __syncthreads();
    }
    const float v204 = __uint_as_float(cand);
    if (tid == 0) cnt = 0;
    __syncthreads();
    int local = 0;
    for (int j = tid; j < SEL_N; j += 256) {
        if (sc[j] > v204) { fl[j] = 1; local++; }
    }
    atomicAdd(&cnt, local);
    __syncthreads();
    if (tid == 0) {
        int need = HEAVY - cnt;
        for (int j = 0; j < SEL_N && need > 0; ++j) {
            if (sc[j] == v204) { fl[j] = 1; --need; }
        }
    }
    __syncthreads();
    float* mask_out = outbuf + 8388608 + h * 2049;
    float* score_out = outbuf + 8388608 + NHEAD * 2049 + h * SEQ;
    for (int j = tid; j < 2049; j += 256) {
        float mv;
        if (j >= 1845) mv = 1.f;
        else if (j < SEL_N) mv = fl[j] ? 1.f : 0.f;
        else mv = 0.f;
        mask_out[j] = mv;
    }
    for (int j = tid; j < SEQ; j += 256) {
        const float cur = (float)colsum[h * SEQ + j];
        const float smv = (j >= SEL_N) ? 1.f : (fl[j] ? 1.f : 0.f);
        score_out[j] = cur * smv;
    }
}

// ---------------------------------------------------------------------------
extern "C" void kernel_launch(void* const* d_in, const int* in_sizes, int n_in,
                              void* d_out, int out_size, void* d_ws, size_t ws_size,
                              hipStream_t stream)
{
    const float* hidden = (const float*)d_in[0];
    const float* Wq = (const float*)d_in[2];
    const float* bq = (const float*)d_in[3];
    const float* Wk = (const float*)d_in[4];
    const float* bk = (const float*)d_in[5];
    const float* Wv = (const float*)d_in[6];
    const float* bv = (const float*)d_in[7];
    const float* Wo = (const float*)d_in[8];
    float* out = (float*)d_out;

    char* ws = (char*)d_ws;
    unsigned short* q_hi = (unsigned short*)(ws);
    unsigned short* q_lo = (unsigned short*)(ws + 16777216);
    unsigned short* k_hi = (unsigned short*)(ws + 33554432);
    unsigned short* k_lo = (unsigned short*)(ws + 37748736);
    unsigned short* v_bf = (unsigned short*)(ws + 41943040);
    unsigned short* vT   = (unsigned short*)(ws + 46137344);
    unsigned short* o_bf = (unsigned short*)(ws + 50331648);
    double* colsum = (double*)(ws + 67633152);

    dim3 blk(256);
    gemm_kernel<false, true, 2, true><<<dim3(32, 16), blk, 0, stream>>>(
        hidden, Wq, bq, q_hi, q_lo, SEQ, HID, HID);
    gemm_kernel<false, true, 2, true><<<dim3(8, 16), blk, 0, stream>>>(
        hidden, Wk, bk, k_hi, k_lo, SEQ, KVHID, HID);
    gemm_kernel<false, false, 0, true><<<dim3(8, 16), blk, 0, stream>>>(
        hidden, Wv, bv, v_bf, nullptr, SEQ, KVHID, HID);
    transpose_v<<<dim3(32, 16), blk, 0, stream>>>(v_bf, vT);
    hipMemsetAsync((void*)colsum, 0, (size_t)NHEAD * SEQ * sizeof(double), stream);
    attn_fused<<<dim3(2048), dim3(64), 0, stream>>>(q_hi, q_lo, k_hi, k_lo, vT, o_bf, colsum);
    topk_kernel<<<dim3(32), blk, 0, stream>>>(colsum, out);
    gemm_kernel<true, false, 1, false><<<dim3(32, 16), blk, 0, stream>>>(
        o_bf, Wo, nullptr, out, nullptr, SEQ, HID, HID);
}

// Round 3
// 1144.130 us; speedup vs baseline: 1.8630x; 1.1531x over previous
//
#include <hip/hip_runtime.h>
#include <stdint.h>

#define SEQ 2048
#define HID 4096
#define KVHID 1024
#define NHEAD 32
#define DHEAD 128
#define HEAVY 204
#define SEL_N 1844

typedef float f32x4 __attribute__((ext_vector_type(4)));
typedef __bf16 bf16x8 __attribute__((ext_vector_type(8)));

#define MFMA16 __builtin_amdgcn_mfma_f32_16x16x32_bf16

__device__ __forceinline__ unsigned short f2bf(float x) {
    unsigned int u = __float_as_uint(x);
    u = (u + 0x7fffu + ((u >> 16) & 1u)) >> 16;
    return (unsigned short)u;
}
__device__ __forceinline__ float bf2f(unsigned short s) {
    return __uint_as_float(((unsigned int)s) << 16);
}
__device__ __forceinline__ unsigned long long pack4(unsigned short a, unsigned short b,
                                                    unsigned short c, unsigned short d) {
    return (unsigned long long)a | ((unsigned long long)b << 16) |
           ((unsigned long long)c << 32) | ((unsigned long long)d << 48);
}
__device__ __forceinline__ float fexp2(float x) {
#if __has_builtin(__builtin_amdgcn_exp2f)
    return __builtin_amdgcn_exp2f(x);
#else
    float r; asm volatile("v_exp_f32 %0, %1\ns_nop 1" : "=v"(r) : "v"(x)); return r;
#endif
}
__device__ __forceinline__ unsigned cvt_pk_bf16(float lo, float hi) {
    unsigned r; asm("v_cvt_pk_bf16_f32 %0, %1, %2" : "=v"(r) : "v"(lo), "v"(hi)); return r;
}
__device__ __forceinline__ void gload_lds16(const unsigned short* g, unsigned short* l) {
    __builtin_amdgcn_global_load_lds(
        (const __attribute__((address_space(1))) void*)g,
        (__attribute__((address_space(3))) void*)l, 16, 0, 0);
}
__device__ __forceinline__ void block_sync() {
    asm volatile("" ::: "memory");
    __builtin_amdgcn_s_barrier();
    asm volatile("" ::: "memory");
}

// ---------------------------------------------------------------------------
// GEMM: C[M,N] = A[M,K] @ B[K,N] (+bias). SPLIT=true: 3-MFMA bf16x2 compensated.
// Tiles 128x128x32, 256 threads.
// ---------------------------------------------------------------------------
template<bool A_BF16, bool SPLIT, int OUTMODE /*0=bf16,1=f32,2=bf16 hi+lo*/, bool BIAS>
__global__ __launch_bounds__(256) void gemm_kernel(
    const void* __restrict__ Aptr, const float* __restrict__ Bmat,
    const float* __restrict__ bias,
    void* __restrict__ C0, unsigned short* __restrict__ C1,
    int M, int N, int K)
{
    constexpr int NBUF = SPLIT ? 4 : 2;
    constexpr int BHI = SPLIT ? 2 : 1;
    __shared__ unsigned short sm[NBUF][128 * 40];

    const int tid = threadIdx.x;
    const int l = tid & 63;
    const int lr = l & 15, lg = l >> 4;
    const int w = tid >> 6;
    const int wm = (w >> 1) * 64, wn = (w & 1) * 64;
    const int m0 = blockIdx.y * 128, n0 = blockIdx.x * 128;

    const f32x4 z4 = {0.f, 0.f, 0.f, 0.f};
    f32x4 acc[4][4];
    #pragma unroll
    for (int i = 0; i < 4; ++i)
        #pragma unroll
        for (int j = 0; j < 4; ++j) acc[i][j] = z4;

    const int arow = tid >> 1, akq = (tid & 1) * 16;
    const int bn = tid & 127, bkh = (tid >> 7) * 16;

    const int nk = K >> 5;
    for (int kt = 0; kt < nk; ++kt) {
        const int k0 = kt << 5;
        __syncthreads();
        if constexpr (A_BF16) {
            const unsigned short* A = (const unsigned short*)Aptr;
            const unsigned short* ap = A + (size_t)(m0 + arow) * K + k0 + akq;
            uint4 v0 = *(const uint4*)(ap);
            uint4 v1 = *(const uint4*)(ap + 8);
            *(uint4*)(&sm[0][arow * 40 + akq]) = v0;
            *(uint4*)(&sm[0][arow * 40 + akq + 8]) = v1;
        } else {
            const float* A = (const float*)Aptr;
            const float* ap = A + (size_t)(m0 + arow) * K + k0 + akq;
            #pragma unroll
            for (int nib = 0; nib < 4; ++nib) {
                float4 v = *(const float4*)(ap + nib * 4);
                unsigned short h0 = f2bf(v.x), h1 = f2bf(v.y), h2 = f2bf(v.z), h3 = f2bf(v.w);
                *(unsigned long long*)(&sm[0][arow * 40 + akq + nib * 4]) = pack4(h0, h1, h2, h3);
                if constexpr (SPLIT) {
                    unsigned short g0 = f2bf(v.x - bf2f(h0)), g1 = f2bf(v.y - bf2f(h1));
                    unsigned short g2 = f2bf(v.z - bf2f(h2)), g3 = f2bf(v.w - bf2f(h3));
                    *(unsigned long long*)(&sm[1][arow * 40 + akq + nib * 4]) = pack4(g0, g1, g2, g3);
                }
            }
        }
        {
            const float* bp = Bmat + (size_t)(k0 + bkh) * N + n0 + bn;
            #pragma unroll
            for (int nib = 0; nib < 4; ++nib) {
                float x0 = bp[(size_t)(nib * 4 + 0) * N];
                float x1 = bp[(size_t)(nib * 4 + 1) * N];
                float x2 = bp[(size_t)(nib * 4 + 2) * N];
                float x3 = bp[(size_t)(nib * 4 + 3) * N];
                unsigned short h0 = f2bf(x0), h1 = f2bf(x1), h2 = f2bf(x2), h3 = f2bf(x3);
                *(unsigned long long*)(&sm[BHI][bn * 40 + bkh + nib * 4]) = pack4(h0, h1, h2, h3);
                if constexpr (SPLIT) {
                    unsigned short g0 = f2bf(x0 - bf2f(h0)), g1 = f2bf(x1 - bf2f(h1));
                    unsigned short g2 = f2bf(x2 - bf2f(h2)), g3 = f2bf(x3 - bf2f(h3));
                    *(unsigned long long*)(&sm[3][bn * 40 + bkh + nib * 4]) = pack4(g0, g1, g2, g3);
                }
            }
        }
        __syncthreads();
        bf16x8 ah[4], bh[4], al[4], bl[4];
        #pragma unroll
        for (int mi = 0; mi < 4; ++mi) {
            int rr = wm + mi * 16 + lr;
            ah[mi] = *(const bf16x8*)(&sm[0][rr * 40 + lg * 8]);
            if constexpr (SPLIT) al[mi] = *(const bf16x8*)(&sm[1][rr * 40 + lg * 8]);
        }
        #pragma unroll
        for (int ni = 0; ni < 4; ++ni) {
            int rr = wn + ni * 16 + lr;
            bh[ni] = *(const bf16x8*)(&sm[BHI][rr * 40 + lg * 8]);
            if constexpr (SPLIT) bl[ni] = *(const bf16x8*)(&sm[3][rr * 40 + lg * 8]);
        }
        #pragma unroll
        for (int mi = 0; mi < 4; ++mi)
            #pragma unroll
            for (int ni = 0; ni < 4; ++ni) {
                acc[mi][ni] = MFMA16(ah[mi], bh[ni], acc[mi][ni], 0, 0, 0);
                if constexpr (SPLIT) {
                    acc[mi][ni] = MFMA16(ah[mi], bl[ni], acc[mi][ni], 0, 0, 0);
                    acc[mi][ni] = MFMA16(al[mi], bh[ni], acc[mi][ni], 0, 0, 0);
                }
            }
    }
    #pragma unroll
    for (int ni = 0; ni < 4; ++ni) {
        const int col = n0 + wn + ni * 16 + lr;
        float bv = 0.f;
        if constexpr (BIAS) bv = bias[col];
        #pragma unroll
        for (int mi = 0; mi < 4; ++mi) {
            #pragma unroll
            for (int r = 0; r < 4; ++r) {
                const int row = m0 + wm + mi * 16 + lg * 4 + r;
                const float x = acc[mi][ni][r] + bv;
                const size_t o = (size_t)row * N + col;
                if constexpr (OUTMODE == 1) {
                    ((float*)C0)[o] = x;
                } else if constexpr (OUTMODE == 0) {
                    ((unsigned short*)C0)[o] = f2bf(x);
                } else {
                    unsigned short hi = f2bf(x);
                    ((unsigned short*)C0)[o] = hi;
                    C1[o] = f2bf(x - bf2f(hi));
                }
            }
        }
    }
}

// ---------------------------------------------------------------------------
// V transpose: v[2048][1024] -> vT[1024][2048] (bf16).
// ---------------------------------------------------------------------------
__global__ __launch_bounds__(256) void transpose_v(const unsigned short* __restrict__ v,
                                                   unsigned short* __restrict__ vt)
{
    __shared__ unsigned short T[64][65];
    const int r0 = blockIdx.x * 64;
    const int c0 = blockIdx.y * 64;
    const int tid = threadIdx.x;
    const int cc = tid & 63, rr = tid >> 6;
    #pragma unroll
    for (int i = 0; i < 16; ++i)
        T[rr + i * 4][cc] = v[(size_t)(r0 + rr + i * 4) * KVHID + c0 + cc];
    __syncthreads();
    #pragma unroll
    for (int i = 0; i < 16; ++i) {
        const int oc = rr + i * 4;
        vt[(size_t)(c0 + oc) * SEQ + r0 + cc] = T[cc][oc];
    }
}

// ---------------------------------------------------------------------------
// Fused attention v2. Block = 256 thr (4 waves), one head, pair of 64-row
// q-blocks (b, 31-b) => uniform 66 k-steps x 2 sweeps per block.
// Wave = 16 q-rows, 16x16x32 MFMAs. K hi/lo tile (32x128x2 = 16KB) staged in
// LDS per k-step via global_load_lds (pre-swizzled source, XOR-swizzled
// ds_read_b128), double-buffered with counted vmcnt(4) + raw barriers.
// Sweep A: row sums l (no max shift; scores bounded). Sweep B: p=e/l, colsum
// (f32 exact per tile + f64 atomics), PV into fp32 accs.
// ---------------------------------------------------------------------------
__device__ __forceinline__ void stage_tile(
    const unsigned short* __restrict__ khi, const unsigned short* __restrict__ klo,
    unsigned short* kb /*[2][32*128] hi,lo*/, int kt, int kvoff, int w, int lane)
{
    const unsigned short* src = (w >> 1) ? klo : khi;
    unsigned short* dst = kb + (w >> 1) * 4096 + (w & 1) * 2048;
    const int lsub = lane >> 4;
    const int lbyte = (lane & 15) * 16;
    #pragma unroll
    for (int j = 0; j < 4; ++j) {
        const int row = (w & 1) * 16 + j * 4 + lsub;
        const int soff = (lbyte ^ ((row & 7) << 4)) >> 1;
        const unsigned short* g = src + (size_t)(kt * 32 + row) * KVHID + kvoff + soff;
        gload_lds16(g, dst + j * 512);
    }
}

__device__ __forceinline__ void process_qblock(
    int head, int qb, int w, int lane,
    const unsigned short* __restrict__ qhi, const unsigned short* __restrict__ qlo,
    const unsigned short* __restrict__ khi, const unsigned short* __restrict__ klo,
    const unsigned short* __restrict__ vT,
    unsigned short* __restrict__ obuf, double* __restrict__ colsum,
    unsigned short* kbuf /*[2][2*4096]*/, unsigned short* pl /*my wave [16][40]*/)
{
    const int lr = lane & 15, lg = lane >> 4;
    const int kv = head >> 2;
    const int kvoff = kv * DHEAD;
    const int q0 = qb * 64;
    const int q0w = q0 + w * 16;
    const int NT = 2 * qb + 2;
    const int wnt = ((q0w + 15) >> 5) + 1;
    const float C = 0.08838834764831845f * 1.44269504088896340f; // scale * log2(e)

    // Q fragments (rows q0w+lr, d = s*32 + lg*8 + j)
    bf16x8 qh[4], qlo4[4];
    {
        const size_t qbase = (size_t)(q0w + lr) * HID + head * DHEAD + lg * 8;
        #pragma unroll
        for (int s = 0; s < 4; ++s) {
            qh[s]   = *(const bf16x8*)(qhi + qbase + s * 32);
            qlo4[s] = *(const bf16x8*)(qlo + qbase + s * 32);
        }
    }
    const int swz = (lr & 7) << 3;  // short-index XOR for K reads (rows lr and 16+lr share it)

    float rl[4];
    // ================= sweep A: row sums =================
    {
        float lp[4] = {0.f, 0.f, 0.f, 0.f};
        stage_tile(khi, klo, kbuf, 0, kvoff, w, lane);
        for (int kt = 0; kt < NT; ++kt) {
            unsigned short* kb = kbuf + (kt & 1) * 8192;
            if (kt + 1 < NT) {
                stage_tile(khi, klo, kbuf + ((kt + 1) & 1) * 8192, kt + 1, kvoff, w, lane);
                asm volatile("s_waitcnt vmcnt(4)" ::: "memory");
            } else {
                asm volatile("s_waitcnt vmcnt(0)" ::: "memory");
            }
            block_sync();
            if (kt < wnt) {
                f32x4 m0 = {}, m1 = {}, x0 = {}, x1 = {};
                #pragma unroll
                for (int s = 0; s < 4; ++s) {
                    const int d = s * 32 + lg * 8;
                    const bf16x8 k0h = *(const bf16x8*)(kb + (lr * 128 + (d ^ swz)));
                    const bf16x8 k1h = *(const bf16x8*)(kb + ((16 + lr) * 128 + (d ^ swz)));
                    const bf16x8 k0l = *(const bf16x8*)(kb + 4096 + lr * 128 + (d ^ swz));
                    const bf16x8 k1l = *(const bf16x8*)(kb + 4096 + (16 + lr) * 128 + (d ^ swz));
                    m0 = MFMA16(qh[s], k0h, m0, 0, 0, 0);
                    m1 = MFMA16(qh[s], k1h, m1, 0, 0, 0);
                    x0 = MFMA16(qlo4[s], k0h, MFMA16(qh[s], k0l, x0, 0, 0, 0), 0, 0, 0);
                    x1 = MFMA16(qlo4[s], k1h, MFMA16(qh[s], k1l, x1, 0, 0, 0), 0, 0, 0);
                }
                const bool full = (kt * 32 + 31 <= q0w);
                #pragma unroll
                for (int r = 0; r < 4; ++r) {
                    float e0 = fexp2((m0[r] + x0[r]) * C);
                    float e1 = fexp2((m1[r] + x1[r]) * C);
                    if (!full) {
                        const int q = q0w + lg * 4 + r;
                        if (kt * 32 + lr > q)      e0 = 0.f;
                        if (kt * 32 + 16 + lr > q) e1 = 0.f;
                    }
                    lp[r] += e0 + e1;
                }
            }
            block_sync();
        }
        #pragma unroll
        for (int r = 0; r < 4; ++r) {
            float v = lp[r];
            v += __shfl_xor(v, 1);
            v += __shfl_xor(v, 2);
            v += __shfl_xor(v, 4);
            v += __shfl_xor(v, 8);
            rl[r] = 1.0f / v;
        }
    }
    // ================= sweep B: p, colsum, PV =================
    {
        f32x4 oacc[8];
        #pragma unroll
        for (int f = 0; f < 8; ++f) oacc[f] = (f32x4){};
        stage_tile(khi, klo, kbuf, 0, kvoff, w, lane);
        for (int kt = 0; kt < NT; ++kt) {
            unsigned short* kb = kbuf + (kt & 1) * 8192;
            if (kt + 1 < NT) {
                stage_tile(khi, klo, kbuf + ((kt + 1) & 1) * 8192, kt + 1, kvoff, w, lane);
                asm volatile("s_waitcnt vmcnt(4)" ::: "memory");
            } else {
                asm volatile("s_waitcnt vmcnt(0)" ::: "memory");
            }
            block_sync();
            if (kt < wnt) {
                f32x4 m0 = {}, m1 = {}, x0 = {}, x1 = {};
                #pragma unroll
                for (int s = 0; s < 4; ++s) {
                    const int d = s * 32 + lg * 8;
                    const bf16x8 k0h = *(const bf16x8*)(kb + (lr * 128 + (d ^ swz)));
                    const bf16x8 k1h = *(const bf16x8*)(kb + ((16 + lr) * 128 + (d ^ swz)));
                    const bf16x8 k0l = *(const bf16x8*)(kb + 4096 + lr * 128 + (d ^ swz));
                    const bf16x8 k1l = *(const bf16x8*)(kb + 4096 + (16 + lr) * 128 + (d ^ swz));
                    m0 = MFMA16(qh[s], k0h, m0, 0, 0, 0);
                    m1 = MFMA16(qh[s], k1h, m1, 0, 0, 0);
                    x0 = MFMA16(qlo4[s], k0h, MFMA16(qh[s], k0l, x0, 0, 0, 0), 0, 0, 0);
                    x1 = MFMA16(qlo4[s], k1h, MFMA16(qh[s], k1l, x1, 0, 0, 0), 0, 0, 0);
                }
                const bool full = (kt * 32 + 31 <= q0w);
                float p0[4], p1[4];
                float cs0 = 0.f, cs1 = 0.f;
                #pragma unroll
                for (int r = 0; r < 4; ++r) {
                    float e0 = fexp2((m0[r] + x0[r]) * C);
                    float e1 = fexp2((m1[r] + x1[r]) * C);
                    if (!full) {
                        const int q = q0w + lg * 4 + r;
                        if (kt * 32 + lr > q)      e0 = 0.f;
                        if (kt * 32 + 16 + lr > q) e1 = 0.f;
                    }
                    p0[r] = e0 * rl[r];
                    p1[r] = e1 * rl[r];
                    cs0 += p0[r];
                    cs1 += p1[r];
                }
                cs0 += __shfl_xor(cs0, 16); cs0 += __shfl_xor(cs0, 32);
                cs1 += __shfl_xor(cs1, 16); cs1 += __shfl_xor(cs1, 32);
                if (lg == 0) {
                    atomicAdd(&colsum[head * SEQ + kt * 32 + lr], (double)cs0);
                    atomicAdd(&colsum[head * SEQ + kt * 32 + 16 + lr], (double)cs1);
                }
                // P -> LDS (per-wave private [16][40])
                #pragma unroll
                for (int r = 0; r < 4; r += 2) {
                    const int row0 = (lg * 4 + r) * 40;
                    unsigned u0 = cvt_pk_bf16(p0[r], p0[r + 1]);
                    unsigned u1 = cvt_pk_bf16(p1[r], p1[r + 1]);
                    pl[row0 + lr]           = (unsigned short)u0;
                    pl[row0 + 40 + lr]      = (unsigned short)(u0 >> 16);
                    pl[row0 + 16 + lr]      = (unsigned short)u1;
                    pl[row0 + 56 + lr]      = (unsigned short)(u1 >> 16);
                }
                const bf16x8 pa = *(const bf16x8*)(pl + lr * 40 + lg * 8);
                #pragma unroll
                for (int f = 0; f < 8; ++f) {
                    const bf16x8 vf = *(const bf16x8*)(vT + (size_t)(kvoff + f * 16 + lr) * SEQ
                                                       + kt * 32 + lg * 8);
                    oacc[f] = MFMA16(pa, vf, oacc[f], 0, 0, 0);
                }
            }
            block_sync();
        }
        #pragma unroll
        for (int f = 0; f < 8; ++f)
            #pragma unroll
            for (int r = 0; r < 4; ++r)
                obuf[(size_t)(q0w + lg * 4 + r) * HID + head * DHEAD + f * 16 + lr] =
                    f2bf(oacc[f][r]);
    }
}

__global__ __launch_bounds__(256, 2) void attn_fused2(
    const unsigned short* __restrict__ qhi, const unsigned short* __restrict__ qlo,
    const unsigned short* __restrict__ khi, const unsigned short* __restrict__ klo,
    const unsigned short* __restrict__ vT,
    unsigned short* __restrict__ obuf, double* __restrict__ colsum)
{
    __shared__ unsigned short kbuf[2][2 * 4096];   // [buf][hi/lo][32*128]
    __shared__ unsigned short plds[4][16 * 40];
    const int head = blockIdx.x >> 4;
    const int pr = blockIdx.x & 15;
    const int tid = threadIdx.x;
    const int w = tid >> 6, lane = tid & 63;
    process_qblock(head, pr, w, lane, qhi, qlo, khi, klo, vT, obuf, colsum,
                   &kbuf[0][0], &plds[w][0]);
    process_qblock(head, 31 - pr, w, lane, qhi, qlo, khi, klo, vT, obuf, colsum,
                   &kbuf[0][0], &plds[w][0]);
}

// ---------------------------------------------------------------------------
// Top-k (204 of 1844) per head, exact jax.lax.top_k semantics (stable ties).
// ---------------------------------------------------------------------------
__global__ __launch_bounds__(256) void topk_kernel(const double* __restrict__ colsum,
                                                   float* __restrict__ outbuf)
{
    __shared__ float sc[SEL_N];
    __shared__ unsigned char fl[SEL_N];
    __shared__ int cnt;
    const int h = blockIdx.x;
    const int tid = threadIdx.x;
    for (int j = tid; j < SEL_N; j += 256) {
        sc[j] = (float)colsum[h * SEQ + j];
        fl[j] = 0;
    }
    __syncthreads();
    unsigned int cand = 0u;
    for (int b = 30; b >= 0; --b) {
        const unsigned int t = cand | (1u << b);
        const float tv = __uint_as_float(t);
        if (tid == 0) cnt = 0;
        __syncthreads();
        int local = 0;
        for (int j = tid; j < SEL_N; j += 256) local += (sc[j] >= tv) ? 1 : 0;
        atomicAdd(&cnt, local);
        __syncthreads();
        if (cnt >= HEAVY) cand = t;
        __syncthreads();
    }
    const float v204 = __uint_as_float(cand);
    if (tid == 0) cnt = 0;
    __syncthreads();
    int local = 0;
    for (int j = tid; j < SEL_N; j += 256) {
        if (sc[j] > v204) { fl[j] = 1; local++; }
    }
    atomicAdd(&cnt, local);
    __syncthreads();
    if (tid == 0) {
        int need = HEAVY - cnt;
        for (int j = 0; j < SEL_N && need > 0; ++j) {
            if (sc[j] == v204) { fl[j] = 1; --need; }
        }
    }
    __syncthreads();
    float* mask_out = outbuf + 8388608 + h * 2049;
    float* score_out = outbuf + 8388608 + NHEAD * 2049 + h * SEQ;
    for (int j = tid; j < 2049; j += 256) {
        float mv;
        if (j >= 1845) mv = 1.f;
        else if (j < SEL_N) mv = fl[j] ? 1.f : 0.f;
        else mv = 0.f;
        mask_out[j] = mv;
    }
    for (int j = tid; j < SEQ; j += 256) {
        const float cur = (float)colsum[h * SEQ + j];
        const float smv = (j >= SEL_N) ? 1.f : (fl[j] ? 1.f : 0.f);
        score_out[j] = cur * smv;
    }
}

// ---------------------------------------------------------------------------
extern "C" void kernel_launch(void* const* d_in, const int* in_sizes, int n_in,
                              void* d_out, int out_size, void* d_ws, size_t ws_size,
                              hipStream_t stream)
{
    const float* hidden = (const float*)d_in[0];
    const float* Wq = (const float*)d_in[2];
    const float* bq = (const float*)d_in[3];
    const float* Wk = (const float*)d_in[4];
    const float* bk = (const float*)d_in[5];
    const float* Wv = (const float*)d_in[6];
    const float* bv = (const float*)d_in[7];
    const float* Wo = (const float*)d_in[8];
    float* out = (float*)d_out;

    char* ws = (char*)d_ws;
    unsigned short* q_hi = (unsigned short*)(ws);
    unsigned short* q_lo = (unsigned short*)(ws + 16777216);
    unsigned short* k_hi = (unsigned short*)(ws + 33554432);
    unsigned short* k_lo = (unsigned short*)(ws + 37748736);
    unsigned short* v_bf = (unsigned short*)(ws + 41943040);
    unsigned short* vT   = (unsigned short*)(ws + 46137344);
    unsigned short* o_bf = (unsigned short*)(ws + 50331648);
    double* colsum = (double*)(ws + 67633152);

    dim3 blk(256);
    gemm_kernel<false, true, 2, true><<<dim3(32, 16), blk, 0, stream>>>(
        hidden, Wq, bq, q_hi, q_lo, SEQ, HID, HID);
    gemm_kernel<false, true, 2, true><<<dim3(8, 16), blk, 0, stream>>>(
        hidden, Wk, bk, k_hi, k_lo, SEQ, KVHID, HID);
    gemm_kernel<false, false, 0, true><<<dim3(8, 16), blk, 0, stream>>>(
        hidden, Wv, bv, v_bf, nullptr, SEQ, KVHID, HID);
    transpose_v<<<dim3(32, 16), blk, 0, stream>>>(v_bf, vT);
    hipMemsetAsync((void*)colsum, 0, (size_t)NHEAD * SEQ * sizeof(double), stream);
    attn_fused2<<<dim3(512), blk, 0, stream>>>(q_hi, q_lo, k_hi, k_lo, vT, o_bf, colsum);
    topk_kernel<<<dim3(32), blk, 0, stream>>>(colsum, out);
    gemm_kernel<true, false, 1, false><<<dim3(32, 16), blk, 0, stream>>>(
        o_bf, Wo, nullptr, out, nullptr, SEQ, HID, HID);
}

// Round 5
// 855.260 us; speedup vs baseline: 2.4923x; 1.3378x over previous
//
#include <hip/hip_runtime.h>
#include <stdint.h>

#define SEQ 2048
#define HID 4096
#define KVHID 1024
#define NHEAD 32
#define DHEAD 128
#define HEAVY 204
#define SEL_N 1844

typedef float f32x4 __attribute__((ext_vector_type(4)));
typedef __bf16 bf16x8 __attribute__((ext_vector_type(8)));

#define MFMA16 __builtin_amdgcn_mfma_f32_16x16x32_bf16

__device__ __forceinline__ unsigned short f2bf(float x) {
    unsigned int u = __float_as_uint(x);
    u = (u + 0x7fffu + ((u >> 16) & 1u)) >> 16;
    return (unsigned short)u;
}
__device__ __forceinline__ float bf2f(unsigned short s) {
    return __uint_as_float(((unsigned int)s) << 16);
}
__device__ __forceinline__ unsigned long long pack4(unsigned short a, unsigned short b,
                                                    unsigned short c, unsigned short d) {
    return (unsigned long long)a | ((unsigned long long)b << 16) |
           ((unsigned long long)c << 32) | ((unsigned long long)d << 48);
}
__device__ __forceinline__ float fexp2(float x) {
#if __has_builtin(__builtin_amdgcn_exp2f)
    return __builtin_amdgcn_exp2f(x);
#else
    float r; asm volatile("v_exp_f32 %0, %1\ns_nop 1" : "=v"(r) : "v"(x)); return r;
#endif
}
__device__ __forceinline__ unsigned cvt_pk_bf16(float lo, float hi) {
    unsigned r; asm("v_cvt_pk_bf16_f32 %0, %1, %2" : "=v"(r) : "v"(lo), "v"(hi)); return r;
}
__device__ __forceinline__ void gload_lds16(const unsigned short* g, unsigned short* l) {
    __builtin_amdgcn_global_load_lds(
        (const __attribute__((address_space(1))) void*)g,
        (__attribute__((address_space(3))) void*)l, 16, 0, 0);
}
__device__ __forceinline__ void block_sync() {
    asm volatile("" ::: "memory");
    __builtin_amdgcn_s_barrier();
    asm volatile("" ::: "memory");
}

// ---------------------------------------------------------------------------
// Prep: split fp32 -> bf16 hi/lo (elementwise), 4 elems/thread/iter.
// ---------------------------------------------------------------------------
__global__ __launch_bounds__(256) void split_f32(const float* __restrict__ in,
    unsigned short* __restrict__ hi, unsigned short* __restrict__ lo, int n4)
{
    int i = blockIdx.x * 256 + threadIdx.x;
    const int stride = gridDim.x * 256;
    for (; i < n4; i += stride) {
        const float4 v = ((const float4*)in)[i];
        const unsigned short h0 = f2bf(v.x), h1 = f2bf(v.y), h2 = f2bf(v.z), h3 = f2bf(v.w);
        ((unsigned long long*)hi)[i] = pack4(h0, h1, h2, h3);
        ((unsigned long long*)lo)[i] = pack4(f2bf(v.x - bf2f(h0)), f2bf(v.y - bf2f(h1)),
                                             f2bf(v.z - bf2f(h2)), f2bf(v.w - bf2f(h3)));
    }
}

// ---------------------------------------------------------------------------
// Prep: W [K][N] fp32 -> W^T [N][K] bf16 (hi, and lo if SPLIT). 64x64 tiles.
// ---------------------------------------------------------------------------
template<bool SPLIT>
__global__ __launch_bounds__(256) void wprep(const float* __restrict__ W,
    unsigned short* __restrict__ Thi, unsigned short* __restrict__ Tlo, int K, int N)
{
    __shared__ float T[64][65];
    const int k0 = blockIdx.y << 6, n0 = blockIdx.x << 6;
    const int tid = threadIdx.x;
    const int c = tid & 63, r4 = tid >> 6;
    #pragma unroll
    for (int i = 0; i < 16; ++i)
        T[r4 + i * 4][c] = W[(size_t)(k0 + r4 + i * 4) * N + n0 + c];
    __syncthreads();
    #pragma unroll
    for (int i = 0; i < 16; ++i) {
        const int n = r4 + i * 4;
        const float x = T[c][n];
        const size_t o = (size_t)(n0 + n) * K + k0 + c;
        const unsigned short h = f2bf(x);
        Thi[o] = h;
        if constexpr (SPLIT) Tlo[o] = f2bf(x - bf2f(h));
    }
}

// ---------------------------------------------------------------------------
// GEMM v2: C[M,N] = A[M,K] @ B^T[N,K] (+bias). All operands pre-split bf16.
// 128x128x32 tiles, 256 thr. global_load_lds(16B) staging, pre-swizzled source
// + XOR-swizzled ds_read_b128, double-buffered, counted vmcnt, raw barriers.
// SPLIT: 3-chain compensated bf16x2 product.
// ---------------------------------------------------------------------------
template<bool SPLIT, int OUTMODE /*0=bf16,1=f32,2=bf16 hi+lo*/, bool BIAS>
__global__ __launch_bounds__(256) void gemm2(
    const unsigned short* __restrict__ Ahi, const unsigned short* __restrict__ Alo,
    const unsigned short* __restrict__ Bhi, const unsigned short* __restrict__ Blo,
    const float* __restrict__ bias,
    void* __restrict__ C0, unsigned short* __restrict__ C1,
    int M, int N, int K)
{
    constexpr int NT = SPLIT ? 4 : 2;
    __shared__ unsigned short sm[2][NT][128 * 32];   // 8KB tiles

    const int tid = threadIdx.x;
    const int l = tid & 63, w = tid >> 6;
    const int lr = l & 15, lg = l >> 4;
    const int wm = (w >> 1) * 64, wn = (w & 1) * 64;
    const int m0 = blockIdx.y * 128, n0 = blockIdx.x * 128;

    const unsigned short* aH = Ahi + (size_t)m0 * K;
    const unsigned short* bH = Bhi + (size_t)n0 * K;
    const unsigned short* aL = SPLIT ? Alo + (size_t)m0 * K : nullptr;
    const unsigned short* bL = SPLIT ? Blo + (size_t)n0 * K : nullptr;

    // per-thread staging slots: s = tid, tid+256; row = s>>2, dst col16 = s&3,
    // src col16 = (s&3) ^ (row&3)  (inverse of the read-side XOR swizzle)
    const int s0_ = tid, s1_ = tid + 256;
    const int r0_ = s0_ >> 2, c0_ = (s0_ & 3) ^ (r0_ & 3);
    const int r1_ = s1_ >> 2, c1_ = (s1_ & 3) ^ (r1_ & 3);
    const size_t g0off = (size_t)r0_ * K + c0_ * 8;
    const size_t g1off = (size_t)r1_ * K + c1_ * 8;

#define STAGE(buf, kk)                                                          \
    do {                                                                        \
        const int k0s = (kk) << 5;                                              \
        gload_lds16(aH + g0off + k0s, &sm[buf][0][s0_ * 8]);                    \
        gload_lds16(aH + g1off + k0s, &sm[buf][0][s1_ * 8]);                    \
        gload_lds16(bH + g0off + k0s, &sm[buf][1][s0_ * 8]);                    \
        gload_lds16(bH + g1off + k0s, &sm[buf][1][s1_ * 8]);                    \
        if constexpr (SPLIT) {                                                  \
            gload_lds16(aL + g0off + k0s, &sm[buf][2][s0_ * 8]);                \
            gload_lds16(aL + g1off + k0s, &sm[buf][2][s1_ * 8]);                \
            gload_lds16(bL + g0off + k0s, &sm[buf][3][s0_ * 8]);                \
            gload_lds16(bL + g1off + k0s, &sm[buf][3][s1_ * 8]);                \
        }                                                                       \
    } while (0)

    f32x4 acc[4][4];
    #pragma unroll
    for (int i = 0; i < 4; ++i)
        #pragma unroll
        for (int j = 0; j < 4; ++j) acc[i][j] = (f32x4){};

    const int nk = K >> 5;
    STAGE(0, 0);
    for (int kt = 0; kt < nk; ++kt) {
        if (kt + 1 < nk) {
            STAGE((kt + 1) & 1, kt + 1);
            if constexpr (SPLIT) asm volatile("s_waitcnt vmcnt(8)" ::: "memory");
            else                 asm volatile("s_waitcnt vmcnt(4)" ::: "memory");
        } else {
            asm volatile("s_waitcnt vmcnt(0)" ::: "memory");
        }
        block_sync();
        {
            const unsigned short (*smb)[128 * 32] = sm[kt & 1];
            bf16x8 ah[4], bh[4], al[4], bl[4];
            #pragma unroll
            for (int mi = 0; mi < 4; ++mi) {
                const int rr = wm + mi * 16 + lr;
                const int o = rr * 32 + ((lg ^ (rr & 3)) << 3);
                ah[mi] = *(const bf16x8*)(&smb[0][o]);
                if constexpr (SPLIT) al[mi] = *(const bf16x8*)(&smb[2][o]);
            }
            #pragma unroll
            for (int ni = 0; ni < 4; ++ni) {
                const int rr = wn + ni * 16 + lr;
                const int o = rr * 32 + ((lg ^ (rr & 3)) << 3);
                bh[ni] = *(const bf16x8*)(&smb[1][o]);
                if constexpr (SPLIT) bl[ni] = *(const bf16x8*)(&smb[3][o]);
            }
            #pragma unroll
            for (int mi = 0; mi < 4; ++mi)
                #pragma unroll
                for (int ni = 0; ni < 4; ++ni) {
                    acc[mi][ni] = MFMA16(ah[mi], bh[ni], acc[mi][ni], 0, 0, 0);
                    if constexpr (SPLIT) {
                        acc[mi][ni] = MFMA16(ah[mi], bl[ni], acc[mi][ni], 0, 0, 0);
                        acc[mi][ni] = MFMA16(al[mi], bh[ni], acc[mi][ni], 0, 0, 0);
                    }
                }
        }
        block_sync();
    }
#undef STAGE

    #pragma unroll
    for (int ni = 0; ni < 4; ++ni) {
        const int col = n0 + wn + ni * 16 + lr;
        float bv = 0.f;
        if constexpr (BIAS) bv = bias[col];
        #pragma unroll
        for (int mi = 0; mi < 4; ++mi) {
            #pragma unroll
            for (int r = 0; r < 4; ++r) {
                const int row = m0 + wm + mi * 16 + lg * 4 + r;
                const float x = acc[mi][ni][r] + bv;
                const size_t o = (size_t)row * N + col;
                if constexpr (OUTMODE == 1) {
                    ((float*)C0)[o] = x;
                } else if constexpr (OUTMODE == 0) {
                    ((unsigned short*)C0)[o] = f2bf(x);
                } else {
                    const unsigned short hi = f2bf(x);
                    ((unsigned short*)C0)[o] = hi;
                    C1[o] = f2bf(x - bf2f(hi));
                }
            }
        }
    }
}

// ---------------------------------------------------------------------------
// V transpose: v[2048][1024] -> vT[1024][2048] (bf16).
// ---------------------------------------------------------------------------
__global__ __launch_bounds__(256) void transpose_v(const unsigned short* __restrict__ v,
                                                   unsigned short* __restrict__ vt)
{
    __shared__ unsigned short T[64][65];
    const int r0 = blockIdx.x * 64;
    const int c0 = blockIdx.y * 64;
    const int tid = threadIdx.x;
    const int cc = tid & 63, rr = tid >> 6;
    #pragma unroll
    for (int i = 0; i < 16; ++i)
        T[rr + i * 4][cc] = v[(size_t)(r0 + rr + i * 4) * KVHID + c0 + cc];
    __syncthreads();
    #pragma unroll
    for (int i = 0; i < 16; ++i) {
        const int oc = rr + i * 4;
        vt[(size_t)(c0 + oc) * SEQ + r0 + cc] = T[cc][oc];
    }
}

// ---------------------------------------------------------------------------
// Fused attention: block = 4 waves, one head, pair of 64-row q-blocks;
// K hi/lo LDS-staged, double-buffered, counted vmcnt.
// ---------------------------------------------------------------------------
__device__ __forceinline__ void stage_tile(
    const unsigned short* __restrict__ khi, const unsigned short* __restrict__ klo,
    unsigned short* kb, int kt, int kvoff, int w, int lane)
{
    const unsigned short* src = (w >> 1) ? klo : khi;
    unsigned short* dst = kb + (w >> 1) * 4096 + (w & 1) * 2048;
    const int lsub = lane >> 4;
    const int lbyte = (lane & 15) * 16;
    #pragma unroll
    for (int j = 0; j < 4; ++j) {
        const int row = (w & 1) * 16 + j * 4 + lsub;
        const int soff = (lbyte ^ ((row & 7) << 4)) >> 1;
        const unsigned short* g = src + (size_t)(kt * 32 + row) * KVHID + kvoff + soff;
        gload_lds16(g, dst + j * 512);
    }
}

__device__ __forceinline__ void process_qblock(
    int head, int qb, int w, int lane,
    const unsigned short* __restrict__ qhi, const unsigned short* __restrict__ qlo,
    const unsigned short* __restrict__ khi, const unsigned short* __restrict__ klo,
    const unsigned short* __restrict__ vT,
    unsigned short* __restrict__ obuf, double* __restrict__ colsum,
    unsigned short* kbuf, unsigned short* pl)
{
    const int lr = lane & 15, lg = lane >> 4;
    const int kv = head >> 2;
    const int kvoff = kv * DHEAD;
    const int q0 = qb * 64;
    const int q0w = q0 + w * 16;
    const int NT = 2 * qb + 2;
    const int wnt = ((q0w + 15) >> 5) + 1;
    const float C = 0.08838834764831845f * 1.44269504088896340f;

    bf16x8 qh[4], qlo4[4];
    {
        const size_t qbase = (size_t)(q0w + lr) * HID + head * DHEAD + lg * 8;
        #pragma unroll
        for (int s = 0; s < 4; ++s) {
            qh[s]   = *(const bf16x8*)(qhi + qbase + s * 32);
            qlo4[s] = *(const bf16x8*)(qlo + qbase + s * 32);
        }
    }
    const int swz = (lr & 7) << 3;

    float rl[4];
    {
        float lp[4] = {0.f, 0.f, 0.f, 0.f};
        stage_tile(khi, klo, kbuf, 0, kvoff, w, lane);
        for (int kt = 0; kt < NT; ++kt) {
            unsigned short* kb = kbuf + (kt & 1) * 8192;
            if (kt + 1 < NT) {
                stage_tile(khi, klo, kbuf + ((kt + 1) & 1) * 8192, kt + 1, kvoff, w, lane);
                asm volatile("s_waitcnt vmcnt(4)" ::: "memory");
            } else {
                asm volatile("s_waitcnt vmcnt(0)" ::: "memory");
            }
            block_sync();
            if (kt < wnt) {
                f32x4 m0 = {}, m1 = {}, x0 = {}, x1 = {};
                #pragma unroll
                for (int s = 0; s < 4; ++s) {
                    const int d = s * 32 + lg * 8;
                    const bf16x8 k0h = *(const bf16x8*)(kb + (lr * 128 + (d ^ swz)));
                    const bf16x8 k1h = *(const bf16x8*)(kb + ((16 + lr) * 128 + (d ^ swz)));
                    const bf16x8 k0l = *(const bf16x8*)(kb + 4096 + lr * 128 + (d ^ swz));
                    const bf16x8 k1l = *(const bf16x8*)(kb + 4096 + (16 + lr) * 128 + (d ^ swz));
                    m0 = MFMA16(qh[s], k0h, m0, 0, 0, 0);
                    m1 = MFMA16(qh[s], k1h, m1, 0, 0, 0);
                    x0 = MFMA16(qlo4[s], k0h, MFMA16(qh[s], k0l, x0, 0, 0, 0), 0, 0, 0);
                    x1 = MFMA16(qlo4[s], k1h, MFMA16(qh[s], k1l, x1, 0, 0, 0), 0, 0, 0);
                }
                const bool full = (kt * 32 + 31 <= q0w);
                #pragma unroll
                for (int r = 0; r < 4; ++r) {
                    float e0 = fexp2((m0[r] + x0[r]) * C);
                    float e1 = fexp2((m1[r] + x1[r]) * C);
                    if (!full) {
                        const int q = q0w + lg * 4 + r;
                        if (kt * 32 + lr > q)      e0 = 0.f;
                        if (kt * 32 + 16 + lr > q) e1 = 0.f;
                    }
                    lp[r] += e0 + e1;
                }
            }
            block_sync();
        }
        #pragma unroll
        for (int r = 0; r < 4; ++r) {
            float v = lp[r];
            v += __shfl_xor(v, 1);
            v += __shfl_xor(v, 2);
            v += __shfl_xor(v, 4);
            v += __shfl_xor(v, 8);
            rl[r] = 1.0f / v;
        }
    }
    {
        f32x4 oacc[8];
        #pragma unroll
        for (int f = 0; f < 8; ++f) oacc[f] = (f32x4){};
        stage_tile(khi, klo, kbuf, 0, kvoff, w, lane);
        for (int kt = 0; kt < NT; ++kt) {
            unsigned short* kb = kbuf + (kt & 1) * 8192;
            if (kt + 1 < NT) {
                stage_tile(khi, klo, kbuf + ((kt + 1) & 1) * 8192, kt + 1, kvoff, w, lane);
                asm volatile("s_waitcnt vmcnt(4)" ::: "memory");
            } else {
                asm volatile("s_waitcnt vmcnt(0)" ::: "memory");
            }
            block_sync();
            if (kt < wnt) {
                f32x4 m0 = {}, m1 = {}, x0 = {}, x1 = {};
                #pragma unroll
                for (int s = 0; s < 4; ++s) {
                    const int d = s * 32 + lg * 8;
                    const bf16x8 k0h = *(const bf16x8*)(kb + (lr * 128 + (d ^ swz)));
                    const bf16x8 k1h = *(const bf16x8*)(kb + ((16 + lr) * 128 + (d ^ swz)));
                    const bf16x8 k0l = *(const bf16x8*)(kb + 4096 + lr * 128 + (d ^ swz));
                    const bf16x8 k1l = *(const bf16x8*)(kb + 4096 + (16 + lr) * 128 + (d ^ swz));
                    m0 = MFMA16(qh[s], k0h, m0, 0, 0, 0);
                    m1 = MFMA16(qh[s], k1h, m1, 0, 0, 0);
                    x0 = MFMA16(qlo4[s], k0h, MFMA16(qh[s], k0l, x0, 0, 0, 0), 0, 0, 0);
                    x1 = MFMA16(qlo4[s], k1h, MFMA16(qh[s], k1l, x1, 0, 0, 0), 0, 0, 0);
                }
                const bool full = (kt * 32 + 31 <= q0w);
                float p0[4], p1[4];
                float cs0 = 0.f, cs1 = 0.f;
                #pragma unroll
                for (int r = 0; r < 4; ++r) {
                    float e0 = fexp2((m0[r] + x0[r]) * C);
                    float e1 = fexp2((m1[r] + x1[r]) * C);
                    if (!full) {
                        const int q = q0w + lg * 4 + r;
                        if (kt * 32 + lr > q)      e0 = 0.f;
                        if (kt * 32 + 16 + lr > q) e1 = 0.f;
                    }
                    p0[r] = e0 * rl[r];
                    p1[r] = e1 * rl[r];
                    cs0 += p0[r];
                    cs1 += p1[r];
                }
                cs0 += __shfl_xor(cs0, 16); cs0 += __shfl_xor(cs0, 32);
                cs1 += __shfl_xor(cs1, 16); cs1 += __shfl_xor(cs1, 32);
                if (lg == 0) {
                    atomicAdd(&colsum[head * SEQ + kt * 32 + lr], (double)cs0);
                    atomicAdd(&colsum[head * SEQ + kt * 32 + 16 + lr], (double)cs1);
                }
                #pragma unroll
                for (int r = 0; r < 4; r += 2) {
                    const int row0 = (lg * 4 + r) * 40;
                    unsigned u0 = cvt_pk_bf16(p0[r], p0[r + 1]);
                    unsigned u1 = cvt_pk_bf16(p1[r], p1[r + 1]);
                    pl[row0 + lr]      = (unsigned short)u0;
                    pl[row0 + 40 + lr] = (unsigned short)(u0 >> 16);
                    pl[row0 + 16 + lr] = (unsigned short)u1;
                    pl[row0 + 56 + lr] = (unsigned short)(u1 >> 16);
                }
                const bf16x8 pa = *(const bf16x8*)(pl + lr * 40 + lg * 8);
                #pragma unroll
                for (int f = 0; f < 8; ++f) {
                    const bf16x8 vf = *(const bf16x8*)(vT + (size_t)(kvoff + f * 16 + lr) * SEQ
                                                       + kt * 32 + lg * 8);
                    oacc[f] = MFMA16(pa, vf, oacc[f], 0, 0, 0);
                }
            }
            block_sync();
        }
        #pragma unroll
        for (int f = 0; f < 8; ++f)
            #pragma unroll
            for (int r = 0; r < 4; ++r)
                obuf[(size_t)(q0w + lg * 4 + r) * HID + head * DHEAD + f * 16 + lr] =
                    f2bf(oacc[f][r]);
    }
}

__global__ __launch_bounds__(256, 2) void attn_fused2(
    const unsigned short* __restrict__ qhi, const unsigned short* __restrict__ qlo,
    const unsigned short* __restrict__ khi, const unsigned short* __restrict__ klo,
    const unsigned short* __restrict__ vT,
    unsigned short* __restrict__ obuf, double* __restrict__ colsum)
{
    __shared__ unsigned short kbuf[2][2 * 4096];
    __shared__ unsigned short plds[4][16 * 40];
    const int head = blockIdx.x >> 4;
    const int pr = blockIdx.x & 15;
    const int tid = threadIdx.x;
    const int w = tid >> 6, lane = tid & 63;
    process_qblock(head, pr, w, lane, qhi, qlo, khi, klo, vT, obuf, colsum,
                   &kbuf[0][0], &plds[w][0]);
    process_qblock(head, 31 - pr, w, lane, qhi, qlo, khi, klo, vT, obuf, colsum,
                   &kbuf[0][0], &plds[w][0]);
}

// ---------------------------------------------------------------------------
// Top-k (204 of 1844) per head, exact jax.lax.top_k semantics (stable ties).
// ---------------------------------------------------------------------------
__global__ __launch_bounds__(256) void topk_kernel(const double* __restrict__ colsum,
                                                   float* __restrict__ outbuf)
{
    __shared__ float sc[SEL_N];
    __shared__ unsigned char fl[SEL_N];
    __shared__ int cnt;
    const int h = blockIdx.x;
    const int tid = threadIdx.x;
    for (int j = tid; j < SEL_N; j += 256) {
        sc[j] = (float)colsum[h * SEQ + j];
        fl[j] = 0;
    }
    __syncthreads();
    unsigned int cand = 0u;
    for (int b = 30; b >= 0; --b) {
        const unsigned int t = cand | (1u << b);
        const float tv = __uint_as_float(t);
        if (tid == 0) cnt = 0;
        __syncthreads();
        int local = 0;
        for (int j = tid; j < SEL_N; j += 256) local += (sc[j] >= tv) ? 1 : 0;
        atomicAdd(&cnt, local);
        __syncthreads();
        if (cnt >= HEAVY) cand = t;
        __syncthreads();
    }
    const float v204 = __uint_as_float(cand);
    if (tid == 0) cnt = 0;
    __syncthreads();
    int local = 0;
    for (int j = tid; j < SEL_N; j += 256) {
        if (sc[j] > v204) { fl[j] = 1; local++; }
    }
    atomicAdd(&cnt, local);
    __syncthreads();
    if (tid == 0) {
        int need = HEAVY - cnt;
        for (int j = 0; j < SEL_N && need > 0; ++j) {
            if (sc[j] == v204) { fl[j] = 1; --need; }
        }
    }
    __syncthreads();
    float* mask_out = outbuf + 8388608 + h * 2049;
    float* score_out = outbuf + 8388608 + NHEAD * 2049 + h * SEQ;
    for (int j = tid; j < 2049; j += 256) {
        float mv;
        if (j >= 1845) mv = 1.f;
        else if (j < SEL_N) mv = fl[j] ? 1.f : 0.f;
        else mv = 0.f;
        mask_out[j] = mv;
    }
    for (int j = tid; j < SEQ; j += 256) {
        const float cur = (float)colsum[h * SEQ + j];
        const float smv = (j >= SEL_N) ? 1.f : (fl[j] ? 1.f : 0.f);
        score_out[j] = cur * smv;
    }
}

// ---------------------------------------------------------------------------
extern "C" void kernel_launch(void* const* d_in, const int* in_sizes, int n_in,
                              void* d_out, int out_size, void* d_ws, size_t ws_size,
                              hipStream_t stream)
{
    const float* hidden = (const float*)d_in[0];
    const float* Wq = (const float*)d_in[2];
    const float* bq = (const float*)d_in[3];
    const float* Wk = (const float*)d_in[4];
    const float* bk = (const float*)d_in[5];
    const float* Wv = (const float*)d_in[6];
    const float* bv = (const float*)d_in[7];
    const float* Wo = (const float*)d_in[8];
    float* out = (float*)d_out;

    char* ws = (char*)d_ws;
    unsigned short* hs_hi = (unsigned short*)(ws);
    unsigned short* hs_lo = (unsigned short*)(ws + 16777216ull);
    unsigned short* wqT_hi = (unsigned short*)(ws + 33554432ull);
    unsigned short* wqT_lo = (unsigned short*)(ws + 67108864ull);
    unsigned short* wkT_hi = (unsigned short*)(ws + 100663296ull);
    unsigned short* wkT_lo = (unsigned short*)(ws + 109051904ull);
    unsigned short* wvT    = (unsigned short*)(ws + 117440512ull);
    unsigned short* q_hi   = (unsigned short*)(ws + 125829120ull);
    unsigned short* q_lo   = (unsigned short*)(ws + 142606336ull);
    unsigned short* k_hi   = (unsigned short*)(ws + 159383552ull);
    unsigned short* k_lo   = (unsigned short*)(ws + 163577856ull);
    unsigned short* v_bf   = (unsigned short*)(ws + 167772160ull);
    unsigned short* vT     = (unsigned short*)(ws + 171966464ull);
    unsigned short* o_bf   = (unsigned short*)(ws + 176160768ull);
    double* colsum         = (double*)(ws + 192937984ull);
    unsigned short* woT    = wqT_hi;   // reuse after Q GEMM (stream-ordered)

    dim3 blk(256);
    split_f32<<<dim3(2048), blk, 0, stream>>>(hidden, hs_hi, hs_lo, (SEQ * HID) / 4);
    wprep<true><<<dim3(64, 64), blk, 0, stream>>>(Wq, wqT_hi, wqT_lo, HID, HID);
    wprep<true><<<dim3(16, 64), blk, 0, stream>>>(Wk, wkT_hi, wkT_lo, HID, KVHID);
    wprep<false><<<dim3(16, 64), blk, 0, stream>>>(Wv, wvT, nullptr, HID, KVHID);

    gemm2<true, 2, true><<<dim3(32, 16), blk, 0, stream>>>(
        hs_hi, hs_lo, wqT_hi, wqT_lo, bq, q_hi, q_lo, SEQ, HID, HID);
    gemm2<true, 2, true><<<dim3(8, 16), blk, 0, stream>>>(
        hs_hi, hs_lo, wkT_hi, wkT_lo, bk, k_hi, k_lo, SEQ, KVHID, HID);
    gemm2<false, 0, true><<<dim3(8, 16), blk, 0, stream>>>(
        hs_hi, nullptr, wvT, nullptr, bv, v_bf, nullptr, SEQ, KVHID, HID);

    transpose_v<<<dim3(32, 16), blk, 0, stream>>>(v_bf, vT);
    (void)hipMemsetAsync((void*)colsum, 0, (size_t)NHEAD * SEQ * sizeof(double), stream);
    attn_fused2<<<dim3(512), blk, 0, stream>>>(q_hi, q_lo, k_hi, k_lo, vT, o_bf, colsum);
    topk_kernel<<<dim3(32), blk, 0, stream>>>(colsum, out);

    wprep<false><<<dim3(64, 64), blk, 0, stream>>>(Wo, woT, nullptr, HID, HID);
    gemm2<false, 1, false><<<dim3(32, 16), blk, 0, stream>>>(
        o_bf, nullptr, woT, nullptr, nullptr, out, nullptr, SEQ, HID, HID);
}